// Round 1
// baseline (532.120 us; speedup 1.0000x reference)
//
#include <hip/hip_runtime.h>
#include <math.h>

// Problem constants
#define BB 16
#define HH 64
#define LL 16384
#define NST 32
#define LC 256
#define CC 64              // LL/LC
#define BL (BB*LL)         // 262144

// ws layout (float offsets). Total ~84 MB.
#define OFF_H   ((size_t)0)                       // h / y1 buffer: 16,777,216 floats
#define OFF_P   ((size_t)16777216)                // chunk states: float2 x 2,097,152
#define OFF_PW  (OFF_P + (size_t)4194304)         // per-state params float4 x 2048
#define OFF_WL  (OFF_PW + (size_t)8192)           // w^Lc: float2 x 2048
#define OFF_GB  (OFF_WL + (size_t)4096)           // FiLM gamma/beta: 2048
#define OFF_BN  (OFF_GB + (size_t)2048)           // BN sum/sumsq: 128
#define OFF_BNF (OFF_BN + (size_t)128)            // BN mean/inv: 128

// ---------------------------------------------------------------------------
// K0: derived S4D params (w, 2*Cd, w^Lc), FiLM gamma/beta, zero BN sums.
// ---------------------------------------------------------------------------
__global__ void k0_setup(const float* __restrict__ log_dt,
                         const float* __restrict__ log_A_real,
                         const float* __restrict__ A_imag,
                         const float* __restrict__ C_re,
                         const float* __restrict__ C_im,
                         const float* __restrict__ cond,
                         const float* __restrict__ film_w,
                         const float* __restrict__ film_b,
                         float* __restrict__ ws) {
    int t = threadIdx.x;
    if (blockIdx.x == 0) {
        float4* pw = (float4*)(ws + OFF_PW);
        float2* wl = (float2*)(ws + OFF_WL);
        for (int k = 0; k < 8; k++) {
            int idx = k * 256 + t;           // state index = ch*32 + n
            int ch = idx >> 5;
            float dt  = expf(log_dt[ch]);
            float are = -expf(log_A_real[idx]);
            float aim = A_imag[idx];
            float dr = are * dt, di = aim * dt;
            float er = expf(dr);
            float wr = er * cosf(di);
            float wi = er * sinf(di);
            // Cd = (C_re + i C_im) * (w - 1) / A ;  A = are + i aim
            float inv = 1.0f / (are * are + aim * aim);
            float gr = ((wr - 1.0f) * are + wi * aim) * inv;
            float gi = (wi * are - (wr - 1.0f) * aim) * inv;
            float cr = C_re[idx], ci = C_im[idx];
            float cdr = cr * gr - ci * gi;
            float cdi = cr * gi + ci * gr;
            pw[idx] = make_float4(wr, wi, 2.0f * cdr, 2.0f * cdi);
            // w^Lc (analytic — phase arg up to ~2500 rad, libm sinf/cosf reduce fine)
            float erL = expf(dr * (float)LC);
            wl[idx] = make_float2(erL * cosf(di * (float)LC), erL * sinf(di * (float)LC));
        }
    } else if (blockIdx.x == 1) {
        float* gb = ws + OFF_GB;
        for (int k = 0; k < 8; k++) {
            int o = k * 256 + t;             // o = b*128 + j
            int b = o >> 7, j = o & 127;
            float acc = film_b[j];
            for (int q = 0; q < 128; q++)
                acc = fmaf(cond[b * 128 + q], film_w[j * 128 + q], acc);
            gb[o] = acc;
        }
    } else {
        if (t < 128) ws[OFF_BN + t] = 0.0f;
    }
}

// ---------------------------------------------------------------------------
// Channel-mix GEMM: dst[b,g,l] = (opt prelu)( sum_h W[g,h]*src[b,h,l] + bias[g] )
// One thread per l; x column (64) in VGPRs; W broadcast from LDS.
// ---------------------------------------------------------------------------
__global__ __launch_bounds__(256) void k_chanmix(const float* __restrict__ src,
                                                 const float* __restrict__ W,
                                                 const float* __restrict__ bias,
                                                 float* __restrict__ dst,
                                                 const float* __restrict__ aptr,
                                                 int do_prelu) {
    __shared__ __align__(16) float Wl[4096];
    __shared__ float bl[64];
    int t = threadIdx.x;
    int bi = blockIdx.x;
    int b = bi >> 6;
    int l = ((bi & 63) << 8) + t;
    for (int i = 0; i < 16; i++) Wl[t + i * 256] = W[t + i * 256];
    if (t < 64) bl[t] = bias[t];
    __syncthreads();
    float a1 = *aptr;
    const float* sp = src + (size_t)b * HH * LL + l;
    float xv[64];
#pragma unroll
    for (int ch = 0; ch < 64; ch++) xv[ch] = sp[(size_t)ch * LL];
    float* dp = dst + (size_t)b * HH * LL + l;
    for (int g = 0; g < 64; g++) {
        float acc = bl[g];
#pragma unroll
        for (int hh = 0; hh < 16; hh++) {
            float4 wv = *(const float4*)&Wl[g * 64 + hh * 4];
            acc = fmaf(wv.x, xv[hh * 4 + 0], acc);
            acc = fmaf(wv.y, xv[hh * 4 + 1], acc);
            acc = fmaf(wv.z, xv[hh * 4 + 2], acc);
            acc = fmaf(wv.w, xv[hh * 4 + 3], acc);
        }
        if (do_prelu) acc = (acc >= 0.0f) ? acc : a1 * acc;
        dp[(size_t)g * LL] = acc;
    }
}

// ---------------------------------------------------------------------------
// K2 phase A: per (b, chunk, ch) compute local chunk-end partial states.
// Block: 128 threads = 32 channels x 4 lanes; 8 complex states per lane.
// ---------------------------------------------------------------------------
__global__ __launch_bounds__(128) void k2_phaseA(float* __restrict__ ws) {
    __shared__ __align__(16) float hl[32 * 260];
    int t = threadIdx.x;
    int bi = blockIdx.x;          // b * 128 + c*2 + half
    int b = bi >> 7;
    int rem = bi & 127;
    int c = rem >> 1;
    int half = rem & 1;
    const float* hbase = ws + OFF_H + ((size_t)b * HH + half * 32) * LL + (size_t)c * LC;
    // stage 32 rows x 256 floats (coalesced float4)
    for (int i = 0; i < 16; i++) {
        int idx = i * 128 + t;    // float4 units, 2048 total
        int chl = idx >> 6;
        int fid = idx & 63;
        float4 v = *(const float4*)(hbase + (size_t)chl * LL + fid * 4);
        *(float4*)&hl[chl * 260 + fid * 4] = v;
    }
    __syncthreads();
    int chl = t >> 2;
    int sub = t & 3;
    int ch = half * 32 + chl;
    const float4* pw = (const float4*)(ws + OFF_PW);
    float wr[8], wi[8], pr[8], pi[8];
#pragma unroll
    for (int k = 0; k < 8; k++) {
        float4 p = pw[ch * 32 + sub * 8 + k];
        wr[k] = p.x; wi[k] = p.y; pr[k] = 0.0f; pi[k] = 0.0f;
    }
    const float* hrow = &hl[chl * 260];
    for (int j = 0; j < LC; j++) {
        float hv = hrow[j];
#pragma unroll
        for (int k = 0; k < 8; k++) {
            float nr = fmaf(wr[k], pr[k], fmaf(-wi[k], pi[k], hv));
            float ni = fmaf(wi[k], pr[k], wr[k] * pi[k]);
            pr[k] = nr; pi[k] = ni;
        }
    }
    float2* P = (float2*)(ws + OFF_P);
    size_t base = ((size_t)b * CC + c) * 2048 + ch * 32 + sub * 8;
#pragma unroll
    for (int k = 0; k < 8; k++) P[base + k] = make_float2(pr[k], pi[k]);
}

// ---------------------------------------------------------------------------
// K3: sequential carry scan over chunks (in-place: P[c] becomes S_in[c]).
// ---------------------------------------------------------------------------
__global__ __launch_bounds__(256) void k3_scan(float* __restrict__ ws) {
    int tid = blockIdx.x * 256 + threadIdx.x;  // 0..32767
    int b = tid >> 11;
    int r = tid & 2047;
    float2* P = (float2*)(ws + OFF_P);
    float2 wl = ((const float2*)(ws + OFF_WL))[r];
    float sr = 0.0f, si = 0.0f;
    for (int c = 0; c < CC; c++) {
        size_t idx = ((size_t)b * CC + c) * 2048 + r;
        float2 pc = P[idx];
        P[idx] = make_float2(sr, si);
        float nr = fmaf(wl.x, sr, fmaf(-wl.y, si, pc.x));
        float ni = fmaf(wl.y, sr, fmaf(wl.x, si, pc.y));
        sr = nr; si = ni;
    }
}

// ---------------------------------------------------------------------------
// K4 phase C: full recurrence with carry-in; y1 = conv + Dskip*h, in-place.
// ---------------------------------------------------------------------------
__global__ __launch_bounds__(128) void k4_phaseC(float* __restrict__ ws,
                                                 const float* __restrict__ Dskip) {
    __shared__ __align__(16) float hl[32 * 260];
    int t = threadIdx.x;
    int bi = blockIdx.x;
    int b = bi >> 7;
    int rem = bi & 127;
    int c = rem >> 1;
    int half = rem & 1;
    float* hbase = ws + OFF_H + ((size_t)b * HH + half * 32) * LL + (size_t)c * LC;
    for (int i = 0; i < 16; i++) {
        int idx = i * 128 + t;
        int chl = idx >> 6;
        int fid = idx & 63;
        float4 v = *(const float4*)(hbase + (size_t)chl * LL + fid * 4);
        *(float4*)&hl[chl * 260 + fid * 4] = v;
    }
    __syncthreads();
    int chl = t >> 2;
    int sub = t & 3;
    int ch = half * 32 + chl;
    const float4* pw = (const float4*)(ws + OFF_PW);
    const float2* P = (const float2*)(ws + OFF_P);
    size_t pbase = ((size_t)b * CC + c) * 2048 + ch * 32 + sub * 8;
    float wr[8], wi[8], cr[8], ci[8], sr[8], si[8];
#pragma unroll
    for (int k = 0; k < 8; k++) {
        float4 p = pw[ch * 32 + sub * 8 + k];
        wr[k] = p.x; wi[k] = p.y; cr[k] = p.z; ci[k] = p.w;
        float2 s0 = P[pbase + k];
        sr[k] = s0.x; si[k] = s0.y;
    }
    float dsk = Dskip[ch];
    float* hrow = &hl[chl * 260];
    for (int j = 0; j < LC; j++) {
        float hv = hrow[j];
        float acc = 0.0f;
#pragma unroll
        for (int k = 0; k < 8; k++) {
            float nr = fmaf(wr[k], sr[k], fmaf(-wi[k], si[k], hv));
            float ni = fmaf(wi[k], sr[k], wr[k] * si[k]);
            sr[k] = nr; si[k] = ni;
            acc = fmaf(cr[k], nr, acc);      // Re(2Cd * s) = cr*sr - ci*si
            acc = fmaf(-ci[k], ni, acc);
        }
        acc += __shfl_xor(acc, 1);
        acc += __shfl_xor(acc, 2);
        if (sub == 0) hrow[j] = fmaf(dsk, hv, acc);
    }
    __syncthreads();
    for (int i = 0; i < 16; i++) {
        int idx = i * 128 + t;
        int chl2 = idx >> 6;
        int fid = idx & 63;
        *(float4*)(hbase + (size_t)chl2 * LL + fid * 4) = *(const float4*)&hl[chl2 * 260 + fid * 4];
    }
}

// ---------------------------------------------------------------------------
// K5b: BN partial sums per channel (one block per (b,ch) row).
// ---------------------------------------------------------------------------
__global__ __launch_bounds__(256) void k5b_bnsum(const float* __restrict__ y2,
                                                 float* __restrict__ ws) {
    int bi = blockIdx.x;      // row = b*64+ch
    int t = threadIdx.x;
    const float4* r4 = (const float4*)(y2 + (size_t)bi * LL);
    float s = 0.0f, ss = 0.0f;
    for (int i = 0; i < 16; i++) {
        float4 v = r4[t + i * 256];
        s += v.x + v.y + v.z + v.w;
        ss += v.x * v.x + v.y * v.y + v.z * v.z + v.w * v.w;
    }
    for (int off = 32; off; off >>= 1) {
        s += __shfl_xor(s, off);
        ss += __shfl_xor(ss, off);
    }
    __shared__ float wsum[4], wsq[4];
    int wv = t >> 6;
    if ((t & 63) == 0) { wsum[wv] = s; wsq[wv] = ss; }
    __syncthreads();
    if (t == 0) {
        float S = wsum[0] + wsum[1] + wsum[2] + wsum[3];
        float SS = wsq[0] + wsq[1] + wsq[2] + wsq[3];
        int ch = bi & 63;
        atomicAdd(ws + OFF_BN + ch, S);
        atomicAdd(ws + OFF_BN + 64 + ch, SS);
    }
}

__global__ void k5c_bnfin(float* __restrict__ ws) {
    int t = threadIdx.x;      // 64 threads
    float cnt = (float)BL;
    float mean = ws[OFF_BN + t] / cnt;
    float var = ws[OFF_BN + 64 + t] / cnt - mean * mean;
    ws[OFF_BNF + t] = mean;
    ws[OFF_BNF + 64 + t] = 1.0f / sqrtf(var + 1e-5f);
}

// ---------------------------------------------------------------------------
// K6: BN apply + FiLM + PReLU + depthwise residual, in-place over d_out.
// ---------------------------------------------------------------------------
__global__ __launch_bounds__(256) void k6_final(const float* __restrict__ x,
                                                const float* __restrict__ ws,
                                                const float* __restrict__ a2p,
                                                const float* __restrict__ res_w,
                                                float* __restrict__ out) {
    int bi = blockIdx.x;      // 16 blocks per row
    int t = threadIdx.x;
    int row = bi >> 4;
    int b = row >> 6, ch = row & 63;
    float gamma = ws[OFF_GB + b * 128 + ch];
    float beta  = ws[OFF_GB + b * 128 + 64 + ch];
    float mean = ws[OFF_BNF + ch];
    float inv  = ws[OFF_BNF + 64 + ch];
    float scale = gamma * inv;
    float shift = beta - scale * mean;
    float rw = res_w[ch];
    float a2 = *a2p;
    size_t i4 = (size_t)row * (LL / 4) + (size_t)(bi & 15) * 256 + t;
    float4 y = ((const float4*)out)[i4];
    float4 xv = ((const float4*)x)[i4];
    float v;
    v = fmaf(scale, y.x, shift); v = (v >= 0.0f) ? v : a2 * v; y.x = fmaf(rw, xv.x, v);
    v = fmaf(scale, y.y, shift); v = (v >= 0.0f) ? v : a2 * v; y.y = fmaf(rw, xv.y, v);
    v = fmaf(scale, y.z, shift); v = (v >= 0.0f) ? v : a2 * v; y.z = fmaf(rw, xv.z, v);
    v = fmaf(scale, y.w, shift); v = (v >= 0.0f) ? v : a2 * v; y.w = fmaf(rw, xv.w, v);
    ((float4*)out)[i4] = y;
}

// ---------------------------------------------------------------------------
extern "C" void kernel_launch(void* const* d_in, const int* in_sizes, int n_in,
                              void* d_out, int out_size, void* d_ws, size_t ws_size,
                              hipStream_t stream) {
    const float* x        = (const float*)d_in[0];
    const float* cond     = (const float*)d_in[1];
    const float* linear_w = (const float*)d_in[2];
    const float* linear_b = (const float*)d_in[3];
    const float* prelu1_a = (const float*)d_in[4];
    const float* log_dt   = (const float*)d_in[5];
    const float* log_A    = (const float*)d_in[6];
    const float* A_imag   = (const float*)d_in[7];
    const float* C_re     = (const float*)d_in[8];
    const float* C_im     = (const float*)d_in[9];
    const float* Dskip    = (const float*)d_in[10];
    const float* out_w    = (const float*)d_in[11];
    const float* out_b    = (const float*)d_in[12];
    const float* film_w   = (const float*)d_in[13];
    const float* film_b   = (const float*)d_in[14];
    const float* prelu2_a = (const float*)d_in[15];
    const float* res_w    = (const float*)d_in[16];
    float* ws  = (float*)d_ws;
    float* out = (float*)d_out;

    hipLaunchKernelGGL(k0_setup, dim3(3), dim3(256), 0, stream,
                       log_dt, log_A, A_imag, C_re, C_im, cond, film_w, film_b, ws);
    // h = prelu(linear_w @ x + b)  -> ws[OFF_H]
    hipLaunchKernelGGL(k_chanmix, dim3(1024), dim3(256), 0, stream,
                       x, linear_w, linear_b, ws + OFF_H, prelu1_a, 1);
    hipLaunchKernelGGL(k2_phaseA, dim3(2048), dim3(128), 0, stream, ws);
    hipLaunchKernelGGL(k3_scan, dim3(128), dim3(256), 0, stream, ws);
    hipLaunchKernelGGL(k4_phaseC, dim3(2048), dim3(128), 0, stream, ws, Dskip);
    // y2 = out_w @ y1 + out_b -> d_out (used as scratch then finalized in place)
    hipLaunchKernelGGL(k_chanmix, dim3(1024), dim3(256), 0, stream,
                       ws + OFF_H, out_w, out_b, out, prelu1_a, 0);
    hipLaunchKernelGGL(k5b_bnsum, dim3(1024), dim3(256), 0, stream, out, ws);
    hipLaunchKernelGGL(k5c_bnfin, dim3(1), dim3(64), 0, stream, ws);
    hipLaunchKernelGGL(k6_final, dim3(16384), dim3(256), 0, stream,
                       x, ws, prelu2_a, res_w, out);
}